// Round 9
// baseline (543.826 us; speedup 1.0000x reference)
//
#include <hip/hip_runtime.h>
#include <hip/hip_bf16.h>

#define N_NODES 50000
#define N_EDGES 800000
#define E_TOTAL (N_EDGES + N_NODES)
#define HEADS 8
#define HD 16
#define C 128            // HEADS*HD == IN_CH
#define NEG_SLOPE 0.2f
#define BN_EPS 1e-5f
#define SCAN_BLKS ((N_NODES + 255) / 256)

__device__ __forceinline__ float blo(unsigned w) { return __uint_as_float(w << 16); }
__device__ __forceinline__ float bhi(unsigned w) { return __uint_as_float(w & 0xffff0000u); }

// ---- 1) h = x @ W (bf16 out) + per-head a_src/a_dst reductions ----
// block = 128 threads (thread = output channel), 16 nodes per block
__global__ __launch_bounds__(128) void k_gemm_att(
    const float* __restrict__ x, const float* __restrict__ W,
    const float* __restrict__ att_src, const float* __restrict__ att_dst,
    __hip_bfloat16* __restrict__ h, float* __restrict__ a_src, float* __restrict__ a_dst) {
  __shared__ float xs[16 * C];
  const int t = threadIdx.x;
  const int node0 = blockIdx.x * 16;
  const float* xsrc = x + (size_t)node0 * C;
#pragma unroll
  for (int i = 0; i < 16; ++i) xs[t + i * 128] = xsrc[t + i * 128];
  __syncthreads();

  float acc[16];
#pragma unroll
  for (int n = 0; n < 16; ++n) acc[n] = 0.f;
  for (int k4 = 0; k4 < 32; ++k4) {
    const float w0 = W[(4 * k4 + 0) * C + t];
    const float w1 = W[(4 * k4 + 1) * C + t];
    const float w2 = W[(4 * k4 + 2) * C + t];
    const float w3 = W[(4 * k4 + 3) * C + t];
#pragma unroll
    for (int n = 0; n < 16; ++n) {
      const float4 xq = *(const float4*)&xs[n * C + 4 * k4];
      acc[n] = fmaf(xq.w, w3, fmaf(xq.z, w2, fmaf(xq.y, w1, fmaf(xq.x, w0, acc[n]))));
    }
  }

  const float asv = att_src[t];
  const float adv = att_dst[t];
#pragma unroll
  for (int n = 0; n < 16; ++n) {
    const int node = node0 + n;
    h[(size_t)node * C + t] = __float2bfloat16(acc[n]);
    float s = acc[n] * asv;
    float d = acc[n] * adv;
#pragma unroll
    for (int off = 8; off >= 1; off >>= 1) {
      s += __shfl_xor(s, off, 16);
      d += __shfl_xor(d, off, 16);
    }
    if ((t & 15) == 0) {
      a_src[node * HEADS + (t >> 4)] = s;
      a_dst[node * HEADS + (t >> 4)] = d;
    }
  }
}

// ---- 2) histogram of dst degrees (incl. self loops) ----
__global__ void k_hist(const int* __restrict__ ei, int* __restrict__ counts) {
  const int e = blockIdx.x * blockDim.x + threadIdx.x;
  if (e >= E_TOTAL) return;
  const int dst = (e < N_EDGES) ? ei[N_EDGES + e] : (e - N_EDGES);
  atomicAdd(&counts[dst], 1);
}

// ---- 3) exclusive scan of counts -> offs ----
__global__ __launch_bounds__(256) void k_scan1(const int* __restrict__ counts,
                                               int* __restrict__ offs,
                                               int* __restrict__ bsums) {
  __shared__ int s[256];
  const int t = threadIdx.x;
  const int i = blockIdx.x * 256 + t;
  const int c = (i < N_NODES) ? counts[i] : 0;
  s[t] = c;
  __syncthreads();
  for (int off = 1; off < 256; off <<= 1) {
    int v = 0;
    if (t >= off) v = s[t - off];
    __syncthreads();
    if (t >= off) s[t] += v;
    __syncthreads();
  }
  if (i < N_NODES) offs[i] = s[t] - c;
  if (t == 255) bsums[blockIdx.x] = s[255];
}

__global__ __launch_bounds__(256) void k_scan2(int* __restrict__ bsums) {
  __shared__ int s[256];
  const int t = threadIdx.x;
  const int c = (t < SCAN_BLKS) ? bsums[t] : 0;
  s[t] = c;
  __syncthreads();
  for (int off = 1; off < 256; off <<= 1) {
    int v = 0;
    if (t >= off) v = s[t - off];
    __syncthreads();
    if (t >= off) s[t] += v;
    __syncthreads();
  }
  if (t < SCAN_BLKS) bsums[t] = s[t] - c;
}

__global__ __launch_bounds__(256) void k_scan3(int* __restrict__ offs,
                                               const int* __restrict__ bsums) {
  const int i = blockIdx.x * 256 + threadIdx.x;
  if (i < N_NODES) offs[i] += bsums[blockIdx.x];
}

// ---- 4) fill CSR (sorted-by-dst source list) ----
__global__ void k_edge_fill(const int* __restrict__ ei,
                            const int* __restrict__ offs, int* __restrict__ cursor,
                            int* __restrict__ srcs_s) {
  const int e = blockIdx.x * blockDim.x + threadIdx.x;
  if (e >= E_TOTAL) return;
  int src, dst;
  if (e < N_EDGES) {
    src = ei[e];
    dst = ei[N_EDGES + e];
  } else {
    src = dst = e - N_EDGES;
  }
  const int pos = offs[dst] + atomicAdd(&cursor[dst], 1);
  srcs_s[pos] = src;
}

// ---- 5) gather aggregate, one node per wave, half-wave per edge ----
// lane = (half, k): half-wave reads a full 256B h-row as 32 x uint2;
// lane k holds channels 4k..4k+3. Main loop: 4 edge rows in flight.
__global__ __launch_bounds__(256) void k_agg(
    const __hip_bfloat16* __restrict__ hb, const int* __restrict__ srcs_s,
    const float* __restrict__ a_src, const float* __restrict__ a_dst,
    const int* __restrict__ offs, const int* __restrict__ counts,
    const float* __restrict__ bias, float* __restrict__ out,
    float* __restrict__ bnsum, float* __restrict__ bnsq) {
  const int t = threadIdx.x;
  const int wv = t >> 6;        // wave 0..3
  const int l = t & 63;
  const int half = l >> 5;      // edge slot within wave
  const int k = l & 31;         // position in half-wave
  const int hh = k >> 2;        // head (4 lanes x 4 ch = 16 ch/head)
  const int c0 = 4 * k;
  const uint2* __restrict__ h4 = (const uint2*)hb;

  const int node = blockIdx.x * 4 + wv;
  const int beg = offs[node];
  const int end = beg + counts[node];
  const float adv = a_dst[node * HEADS + hh];

  float a0 = 0.f, a1 = 0.f, a2 = 0.f, a3 = 0.f, den = 0.f;
  int j = beg + half;
  for (; j + 2 < end; j += 4) {   // this half: edges j, j+2
    const int s0 = srcs_s[j];
    const int s1 = srcs_s[j + 2];
    float v0 = a_src[s0 * HEADS + hh] + adv;
    float v1 = a_src[s1 * HEADS + hh] + adv;
    v0 = (v0 > 0.f) ? v0 : NEG_SLOPE * v0;
    v1 = (v1 > 0.f) ? v1 : NEG_SLOPE * v1;
    const uint2 w0 = h4[(size_t)s0 * 32 + k];
    const uint2 w1 = h4[(size_t)s1 * 32 + k];
    const float e0 = __expf(v0);
    const float e1 = __expf(v1);
    den += e0 + e1;
    a0 = fmaf(e0, blo(w0.x), a0);
    a1 = fmaf(e0, bhi(w0.x), a1);
    a2 = fmaf(e0, blo(w0.y), a2);
    a3 = fmaf(e0, bhi(w0.y), a3);
    a0 = fmaf(e1, blo(w1.x), a0);
    a1 = fmaf(e1, bhi(w1.x), a1);
    a2 = fmaf(e1, blo(w1.y), a2);
    a3 = fmaf(e1, bhi(w1.y), a3);
  }
  if (j < end) {                  // tail edge for this half
    const int s0 = srcs_s[j];
    float v0 = a_src[s0 * HEADS + hh] + adv;
    v0 = (v0 > 0.f) ? v0 : NEG_SLOPE * v0;
    const uint2 w0 = h4[(size_t)s0 * 32 + k];
    const float e0 = __expf(v0);
    den += e0;
    a0 = fmaf(e0, blo(w0.x), a0);
    a1 = fmaf(e0, bhi(w0.x), a1);
    a2 = fmaf(e0, blo(w0.y), a2);
    a3 = fmaf(e0, bhi(w0.y), a3);
  }

  // merge the two half-waves (lane k <-> lane k+32 hold the same channels)
  den += __shfl_xor(den, 32);
  a0 += __shfl_xor(a0, 32);
  a1 += __shfl_xor(a1, 32);
  a2 += __shfl_xor(a2, 32);
  a3 += __shfl_xor(a3, 32);

  const float inv = 1.f / (den + 1e-16f);
  const float4 bv = ((const float4*)bias)[k];
  float4 o;
  o.x = fmaf(a0, inv, bv.x);
  o.y = fmaf(a1, inv, bv.y);
  o.z = fmaf(a2, inv, bv.z);
  o.w = fmaf(a3, inv, bv.w);

  __shared__ float red[4][256];
  if (half == 0) {
    ((float4*)out)[(size_t)node * 32 + k] = o;
    red[wv][c0 + 0] = o.x;
    red[wv][c0 + 1] = o.y;
    red[wv][c0 + 2] = o.z;
    red[wv][c0 + 3] = o.w;
    red[wv][128 + c0 + 0] = o.x * o.x;
    red[wv][128 + c0 + 1] = o.y * o.y;
    red[wv][128 + c0 + 2] = o.z * o.z;
    red[wv][128 + c0 + 3] = o.w * o.w;
  }
  __syncthreads();
  const float sv = red[0][t] + red[1][t] + red[2][t] + red[3][t];
  if (t < 128) atomicAdd(&bnsum[t], sv);
  else atomicAdd(&bnsq[t - 128], sv);
}

// ---- 6) finalize BN scale/shift ----
__global__ __launch_bounds__(128) void k_bnfin(const float* __restrict__ bnsum,
                                               const float* __restrict__ bnsq,
                                               const float* __restrict__ gamma,
                                               const float* __restrict__ beta,
                                               float* __restrict__ scale,
                                               float* __restrict__ shift) {
  const int t = threadIdx.x;
  const float invN = 1.0f / (float)N_NODES;
  const float mean = bnsum[t] * invN;
  const float var = bnsq[t] * invN - mean * mean;
  const float sc = gamma[t] * rsqrtf(var + BN_EPS);
  scale[t] = sc;
  shift[t] = beta[t] - mean * sc;
}

// ---- 7) normalize + ReLU ----
__global__ __launch_bounds__(256) void k_norm(float* __restrict__ out,
                                              const float* __restrict__ scale,
                                              const float* __restrict__ shift) {
  const int i = blockIdx.x * blockDim.x + threadIdx.x;
  if (i >= N_NODES * C / 4) return;
  float4 v = ((float4*)out)[i];
  const int c4 = i & 31;
  const float4 sc = ((const float4*)scale)[c4];
  const float4 sh = ((const float4*)shift)[c4];
  v.x = fmaxf(0.f, fmaf(v.x, sc.x, sh.x));
  v.y = fmaxf(0.f, fmaf(v.y, sc.y, sh.y));
  v.z = fmaxf(0.f, fmaf(v.z, sc.z, sh.z));
  v.w = fmaxf(0.f, fmaf(v.w, sc.w, sh.w));
  ((float4*)out)[i] = v;
}

extern "C" void kernel_launch(void* const* d_in, const int* in_sizes, int n_in,
                              void* d_out, int out_size, void* d_ws, size_t ws_size,
                              hipStream_t stream) {
  const float* x = (const float*)d_in[0];
  const int* ei = (const int*)d_in[1];
  const float* W = (const float*)d_in[2];
  const float* att_src = (const float*)d_in[3];
  const float* att_dst = (const float*)d_in[4];
  const float* bias = (const float*)d_in[5];
  const float* gamma = (const float*)d_in[6];
  const float* beta = (const float*)d_in[7];
  float* out = (float*)d_out;

  char* base = (char*)d_ws;
  size_t off = 0;
  auto alloc = [&](size_t bytes) {
    void* p = base + off;
    off = (off + bytes + 255) & ~(size_t)255;
    return p;
  };

  __hip_bfloat16* hb = (__hip_bfloat16*)alloc((size_t)N_NODES * C * 2);
  float* a_src = (float*)alloc((size_t)N_NODES * HEADS * 4);
  float* a_dst = (float*)alloc((size_t)N_NODES * HEADS * 4);
  int* srcs_s = (int*)alloc((size_t)E_TOTAL * 4);
  int* offs = (int*)alloc((size_t)N_NODES * 4);
  int* bsums = (int*)alloc(256 * 4);
  float* scale = (float*)alloc(C * 4);
  float* shift = (float*)alloc(C * 4);
  // ---- zeroed region (single memset) ----
  const size_t zoff = off;
  int* counts = (int*)alloc((size_t)N_NODES * 4);
  int* cursor = (int*)alloc((size_t)N_NODES * 4);
  float* bnsum = (float*)alloc(C * 4);
  float* bnsq = (float*)alloc(C * 4);
  const size_t zbytes = off - zoff;
  hipMemsetAsync(base + zoff, 0, zbytes, stream);

  k_gemm_att<<<N_NODES / 16, 128, 0, stream>>>(x, W, att_src, att_dst, hb, a_src, a_dst);
  k_hist<<<(E_TOTAL + 255) / 256, 256, 0, stream>>>(ei, counts);
  k_scan1<<<SCAN_BLKS, 256, 0, stream>>>(counts, offs, bsums);
  k_scan2<<<1, 256, 0, stream>>>(bsums);
  k_scan3<<<SCAN_BLKS, 256, 0, stream>>>(offs, bsums);
  k_edge_fill<<<(E_TOTAL + 255) / 256, 256, 0, stream>>>(ei, offs, cursor, srcs_s);
  k_agg<<<N_NODES / 4, 256, 0, stream>>>(hb, srcs_s, a_src, a_dst, offs, counts, bias, out,
                                         bnsum, bnsq);
  k_bnfin<<<1, 128, 0, stream>>>(bnsum, bnsq, gamma, beta, scale, shift);
  k_norm<<<(N_NODES * C / 4 + 255) / 256, 256, 0, stream>>>(out, scale, shift);
}

// Round 10
// 300.908 us; speedup vs baseline: 1.8073x; 1.8073x over previous
//
#include <hip/hip_runtime.h>
#include <hip/hip_bf16.h>

#define N_NODES 50000
#define N_EDGES 800000
#define E_TOTAL (N_EDGES + N_NODES)
#define HEADS 8
#define HD 16
#define C 128            // HEADS*HD == IN_CH
#define NEG_SLOPE 0.2f
#define BN_EPS 1e-5f
#define SCAN_BLKS ((N_NODES + 255) / 256)

__device__ __forceinline__ float blo(unsigned w) { return __uint_as_float(w << 16); }
__device__ __forceinline__ float bhi(unsigned w) { return __uint_as_float(w & 0xffff0000u); }

// ---- 1) h = x @ W (bf16 out) + per-head a_src/a_dst reductions ----
// block = 128 threads (thread = output channel), 16 nodes per block
__global__ __launch_bounds__(128) void k_gemm_att(
    const float* __restrict__ x, const float* __restrict__ W,
    const float* __restrict__ att_src, const float* __restrict__ att_dst,
    __hip_bfloat16* __restrict__ h, float* __restrict__ a_src, float* __restrict__ a_dst) {
  __shared__ float xs[16 * C];
  const int t = threadIdx.x;
  const int node0 = blockIdx.x * 16;
  const float* xsrc = x + (size_t)node0 * C;
#pragma unroll
  for (int i = 0; i < 16; ++i) xs[t + i * 128] = xsrc[t + i * 128];
  __syncthreads();

  float acc[16];
#pragma unroll
  for (int n = 0; n < 16; ++n) acc[n] = 0.f;
  for (int k4 = 0; k4 < 32; ++k4) {
    const float w0 = W[(4 * k4 + 0) * C + t];
    const float w1 = W[(4 * k4 + 1) * C + t];
    const float w2 = W[(4 * k4 + 2) * C + t];
    const float w3 = W[(4 * k4 + 3) * C + t];
#pragma unroll
    for (int n = 0; n < 16; ++n) {
      const float4 xq = *(const float4*)&xs[n * C + 4 * k4];
      acc[n] = fmaf(xq.w, w3, fmaf(xq.z, w2, fmaf(xq.y, w1, fmaf(xq.x, w0, acc[n]))));
    }
  }

  const float asv = att_src[t];
  const float adv = att_dst[t];
#pragma unroll
  for (int n = 0; n < 16; ++n) {
    const int node = node0 + n;
    h[(size_t)node * C + t] = __float2bfloat16(acc[n]);
    float s = acc[n] * asv;
    float d = acc[n] * adv;
#pragma unroll
    for (int off = 8; off >= 1; off >>= 1) {
      s += __shfl_xor(s, off, 16);
      d += __shfl_xor(d, off, 16);
    }
    if ((t & 15) == 0) {
      a_src[node * HEADS + (t >> 4)] = s;
      a_dst[node * HEADS + (t >> 4)] = d;
    }
  }
}

// ---- 2) histogram of dst degrees (incl. self loops) ----
__global__ void k_hist(const int* __restrict__ ei, int* __restrict__ counts) {
  const int e = blockIdx.x * blockDim.x + threadIdx.x;
  if (e >= E_TOTAL) return;
  const int dst = (e < N_EDGES) ? ei[N_EDGES + e] : (e - N_EDGES);
  atomicAdd(&counts[dst], 1);
}

// ---- 3) exclusive scan of counts -> offs ----
__global__ __launch_bounds__(256) void k_scan1(const int* __restrict__ counts,
                                               int* __restrict__ offs,
                                               int* __restrict__ bsums) {
  __shared__ int s[256];
  const int t = threadIdx.x;
  const int i = blockIdx.x * 256 + t;
  const int c = (i < N_NODES) ? counts[i] : 0;
  s[t] = c;
  __syncthreads();
  for (int off = 1; off < 256; off <<= 1) {
    int v = 0;
    if (t >= off) v = s[t - off];
    __syncthreads();
    if (t >= off) s[t] += v;
    __syncthreads();
  }
  if (i < N_NODES) offs[i] = s[t] - c;
  if (t == 255) bsums[blockIdx.x] = s[255];
}

__global__ __launch_bounds__(256) void k_scan2(int* __restrict__ bsums) {
  __shared__ int s[256];
  const int t = threadIdx.x;
  const int c = (t < SCAN_BLKS) ? bsums[t] : 0;
  s[t] = c;
  __syncthreads();
  for (int off = 1; off < 256; off <<= 1) {
    int v = 0;
    if (t >= off) v = s[t - off];
    __syncthreads();
    if (t >= off) s[t] += v;
    __syncthreads();
  }
  if (t < SCAN_BLKS) bsums[t] = s[t] - c;
}

__global__ __launch_bounds__(256) void k_scan3(int* __restrict__ offs,
                                               const int* __restrict__ bsums) {
  const int i = blockIdx.x * 256 + threadIdx.x;
  if (i < N_NODES) offs[i] += bsums[blockIdx.x];
}

// ---- 4) fill CSR (sorted-by-dst source list) ----
__global__ void k_edge_fill(const int* __restrict__ ei,
                            const int* __restrict__ offs, int* __restrict__ cursor,
                            int* __restrict__ srcs_s) {
  const int e = blockIdx.x * blockDim.x + threadIdx.x;
  if (e >= E_TOTAL) return;
  int src, dst;
  if (e < N_EDGES) {
    src = ei[e];
    dst = ei[N_EDGES + e];
  } else {
    src = dst = e - N_EDGES;
  }
  const int pos = offs[dst] + atomicAdd(&cursor[dst], 1);
  srcs_s[pos] = src;
}

// ---- 5) gather aggregate, one node per wave, half-wave per edge ----
// PURE gather + out write: no BN atomics here (they serialized R6/R9).
__global__ __launch_bounds__(256) void k_agg(
    const __hip_bfloat16* __restrict__ hb, const int* __restrict__ srcs_s,
    const float* __restrict__ a_src, const float* __restrict__ a_dst,
    const int* __restrict__ offs, const int* __restrict__ counts,
    const float* __restrict__ bias, float* __restrict__ out) {
  const int t = threadIdx.x;
  const int wv = t >> 6;        // wave 0..3
  const int l = t & 63;
  const int half = l >> 5;      // edge slot within wave
  const int k = l & 31;         // position in half-wave
  const int hh = k >> 2;        // head (4 lanes x 4 ch = 16 ch/head)
  const uint2* __restrict__ h4 = (const uint2*)hb;

  const int node = blockIdx.x * 4 + wv;
  const int beg = offs[node];
  const int end = beg + counts[node];
  const float adv = a_dst[node * HEADS + hh];

  float a0 = 0.f, a1 = 0.f, a2 = 0.f, a3 = 0.f, den = 0.f;
  int j = beg + half;
  for (; j + 2 < end; j += 4) {   // this half: edges j, j+2
    const int s0 = srcs_s[j];
    const int s1 = srcs_s[j + 2];
    float v0 = a_src[s0 * HEADS + hh] + adv;
    float v1 = a_src[s1 * HEADS + hh] + adv;
    v0 = (v0 > 0.f) ? v0 : NEG_SLOPE * v0;
    v1 = (v1 > 0.f) ? v1 : NEG_SLOPE * v1;
    const uint2 w0 = h4[(size_t)s0 * 32 + k];
    const uint2 w1 = h4[(size_t)s1 * 32 + k];
    const float e0 = __expf(v0);
    const float e1 = __expf(v1);
    den += e0 + e1;
    a0 = fmaf(e0, blo(w0.x), a0);
    a1 = fmaf(e0, bhi(w0.x), a1);
    a2 = fmaf(e0, blo(w0.y), a2);
    a3 = fmaf(e0, bhi(w0.y), a3);
    a0 = fmaf(e1, blo(w1.x), a0);
    a1 = fmaf(e1, bhi(w1.x), a1);
    a2 = fmaf(e1, blo(w1.y), a2);
    a3 = fmaf(e1, bhi(w1.y), a3);
  }
  if (j < end) {                  // tail edge for this half
    const int s0 = srcs_s[j];
    float v0 = a_src[s0 * HEADS + hh] + adv;
    v0 = (v0 > 0.f) ? v0 : NEG_SLOPE * v0;
    const uint2 w0 = h4[(size_t)s0 * 32 + k];
    const float e0 = __expf(v0);
    den += e0;
    a0 = fmaf(e0, blo(w0.x), a0);
    a1 = fmaf(e0, bhi(w0.x), a1);
    a2 = fmaf(e0, blo(w0.y), a2);
    a3 = fmaf(e0, bhi(w0.y), a3);
  }

  // merge the two half-waves (lane k <-> lane k+32 hold the same channels)
  den += __shfl_xor(den, 32);
  a0 += __shfl_xor(a0, 32);
  a1 += __shfl_xor(a1, 32);
  a2 += __shfl_xor(a2, 32);
  a3 += __shfl_xor(a3, 32);

  if (half == 0) {
    const float inv = 1.f / (den + 1e-16f);
    const float4 bv = ((const float4*)bias)[k];
    float4 o;
    o.x = fmaf(a0, inv, bv.x);
    o.y = fmaf(a1, inv, bv.y);
    o.z = fmaf(a2, inv, bv.z);
    o.w = fmaf(a3, inv, bv.w);
    ((float4*)out)[(size_t)node * 32 + k] = o;
  }
}

// ---- 5b) BN stats: grid-stride column sums over out ----
// 256 blocks x 256 threads: thread (rr=t>>7, c=t&127) sums rows
// blockIdx*2+rr, stride gridDim*2, channel c. Coalesced 512B/row.
__global__ __launch_bounds__(256) void k_bnstat(const float* __restrict__ out,
                                                float* __restrict__ bnsum,
                                                float* __restrict__ bnsq) {
  const int c = threadIdx.x & 127;
  const int rr = threadIdx.x >> 7;
  float s = 0.f, q = 0.f;
  for (int r = blockIdx.x * 2 + rr; r < N_NODES; r += gridDim.x * 2) {
    const float v = out[(size_t)r * C + c];
    s += v;
    q = fmaf(v, v, q);
  }
  __shared__ float sh[2][128], qh[2][128];
  sh[rr][c] = s;
  qh[rr][c] = q;
  __syncthreads();
  if (threadIdx.x < 128) {
    atomicAdd(&bnsum[c], sh[0][c] + sh[1][c]);
    atomicAdd(&bnsq[c], qh[0][c] + qh[1][c]);
  }
}

// ---- 6) finalize BN scale/shift ----
__global__ __launch_bounds__(128) void k_bnfin(const float* __restrict__ bnsum,
                                               const float* __restrict__ bnsq,
                                               const float* __restrict__ gamma,
                                               const float* __restrict__ beta,
                                               float* __restrict__ scale,
                                               float* __restrict__ shift) {
  const int t = threadIdx.x;
  const float invN = 1.0f / (float)N_NODES;
  const float mean = bnsum[t] * invN;
  const float var = bnsq[t] * invN - mean * mean;
  const float sc = gamma[t] * rsqrtf(var + BN_EPS);
  scale[t] = sc;
  shift[t] = beta[t] - mean * sc;
}

// ---- 7) normalize + ReLU ----
__global__ __launch_bounds__(256) void k_norm(float* __restrict__ out,
                                              const float* __restrict__ scale,
                                              const float* __restrict__ shift) {
  const int i = blockIdx.x * blockDim.x + threadIdx.x;
  if (i >= N_NODES * C / 4) return;
  float4 v = ((float4*)out)[i];
  const int c4 = i & 31;
  const float4 sc = ((const float4*)scale)[c4];
  const float4 sh = ((const float4*)shift)[c4];
  v.x = fmaxf(0.f, fmaf(v.x, sc.x, sh.x));
  v.y = fmaxf(0.f, fmaf(v.y, sc.y, sh.y));
  v.z = fmaxf(0.f, fmaf(v.z, sc.z, sh.z));
  v.w = fmaxf(0.f, fmaf(v.w, sc.w, sh.w));
  ((float4*)out)[i] = v;
}

extern "C" void kernel_launch(void* const* d_in, const int* in_sizes, int n_in,
                              void* d_out, int out_size, void* d_ws, size_t ws_size,
                              hipStream_t stream) {
  const float* x = (const float*)d_in[0];
  const int* ei = (const int*)d_in[1];
  const float* W = (const float*)d_in[2];
  const float* att_src = (const float*)d_in[3];
  const float* att_dst = (const float*)d_in[4];
  const float* bias = (const float*)d_in[5];
  const float* gamma = (const float*)d_in[6];
  const float* beta = (const float*)d_in[7];
  float* out = (float*)d_out;

  char* base = (char*)d_ws;
  size_t off = 0;
  auto alloc = [&](size_t bytes) {
    void* p = base + off;
    off = (off + bytes + 255) & ~(size_t)255;
    return p;
  };

  __hip_bfloat16* hb = (__hip_bfloat16*)alloc((size_t)N_NODES * C * 2);
  float* a_src = (float*)alloc((size_t)N_NODES * HEADS * 4);
  float* a_dst = (float*)alloc((size_t)N_NODES * HEADS * 4);
  int* srcs_s = (int*)alloc((size_t)E_TOTAL * 4);
  int* offs = (int*)alloc((size_t)N_NODES * 4);
  int* bsums = (int*)alloc(256 * 4);
  float* scale = (float*)alloc(C * 4);
  float* shift = (float*)alloc(C * 4);
  // ---- zeroed region (single memset) ----
  const size_t zoff = off;
  int* counts = (int*)alloc((size_t)N_NODES * 4);
  int* cursor = (int*)alloc((size_t)N_NODES * 4);
  float* bnsum = (float*)alloc(C * 4);
  float* bnsq = (float*)alloc(C * 4);
  const size_t zbytes = off - zoff;
  hipMemsetAsync(base + zoff, 0, zbytes, stream);

  k_gemm_att<<<N_NODES / 16, 128, 0, stream>>>(x, W, att_src, att_dst, hb, a_src, a_dst);
  k_hist<<<(E_TOTAL + 255) / 256, 256, 0, stream>>>(ei, counts);
  k_scan1<<<SCAN_BLKS, 256, 0, stream>>>(counts, offs, bsums);
  k_scan2<<<1, 256, 0, stream>>>(bsums);
  k_scan3<<<SCAN_BLKS, 256, 0, stream>>>(offs, bsums);
  k_edge_fill<<<(E_TOTAL + 255) / 256, 256, 0, stream>>>(ei, offs, cursor, srcs_s);
  k_agg<<<N_NODES / 4, 256, 0, stream>>>(hb, srcs_s, a_src, a_dst, offs, counts, bias, out);
  k_bnstat<<<256, 256, 0, stream>>>(out, bnsum, bnsq);
  k_bnfin<<<1, 128, 0, stream>>>(bnsum, bnsq, gamma, beta, scale, shift);
  k_norm<<<(N_NODES * C / 4 + 255) / 256, 256, 0, stream>>>(out, scale, shift);
}

// Round 15
// 280.847 us; speedup vs baseline: 1.9364x; 1.0714x over previous
//
#include <hip/hip_runtime.h>
#include <hip/hip_bf16.h>

#define N_NODES 50000
#define N_EDGES 800000
#define E_TOTAL (N_EDGES + N_NODES)
#define HEADS 8
#define HD 16
#define C 128            // HEADS*HD == IN_CH
#define NEG_SLOPE 0.2f
#define BN_EPS 1e-5f
#define SCAN_BLKS ((N_NODES + 255) / 256)
#define XB_BLKS 3125     // N_NODES*C/(256*8)
#define WT_BLKS 72       // 144*128/256

typedef __bf16 bf16x8 __attribute__((ext_vector_type(8)));
typedef float f32x4 __attribute__((ext_vector_type(4)));

__device__ __forceinline__ float blo(unsigned w) { return __uint_as_float(w << 16); }
__device__ __forceinline__ float bhi(unsigned w) { return __uint_as_float(w & 0xffff0000u); }
__device__ __forceinline__ unsigned short f2b(float f) {  // RNE f32->bf16 bits
  unsigned u = __float_as_uint(f);
  return (unsigned short)((u + 0x7fffu + ((u >> 16) & 1u)) >> 16);
}

// ---- 0) prep: x -> bf16; Wt[144][128] = [W^T ; wsrc ; wdst] in bf16 ----
__global__ __launch_bounds__(256) void k_prep(
    const float* __restrict__ x, const float* __restrict__ W,
    const float* __restrict__ att_src, const float* __restrict__ att_dst,
    unsigned short* __restrict__ xb, unsigned short* __restrict__ wt) {
  const int b = blockIdx.x;
  const int t = threadIdx.x;
  if (b < XB_BLKS) {
    const size_t i0 = ((size_t)b * 256 + t) * 8;
    const float4 f0 = *(const float4*)(x + i0);
    const float4 f1 = *(const float4*)(x + i0 + 4);
    unsigned r0 = (unsigned)f2b(f0.x) | ((unsigned)f2b(f0.y) << 16);
    unsigned r1 = (unsigned)f2b(f0.z) | ((unsigned)f2b(f0.w) << 16);
    unsigned r2 = (unsigned)f2b(f1.x) | ((unsigned)f2b(f1.y) << 16);
    unsigned r3 = (unsigned)f2b(f1.z) | ((unsigned)f2b(f1.w) << 16);
    uint4 o; o.x = r0; o.y = r1; o.z = r2; o.w = r3;
    *(uint4*)(xb + i0) = o;
  } else {
    const int idx = (b - XB_BLKS) * 256 + t;   // 0..18431
    const int n = idx >> 7;
    const int k = idx & 127;
    float v;
    if (n < 128) {
      v = W[k * 128 + n];
    } else if (n < 136) {
      const int hh = n - 128;
      v = 0.f;
#pragma unroll
      for (int d = 0; d < 16; ++d) v = fmaf(W[k * 128 + hh * 16 + d], att_src[hh * 16 + d], v);
    } else {
      const int hh = n - 136;
      v = 0.f;
#pragma unroll
      for (int d = 0; d < 16; ++d) v = fmaf(W[k * 128 + hh * 16 + d], att_dst[hh * 16 + d], v);
    }
    wt[n * 128 + k] = f2b(v);
  }
}

// ---- 1) h = x @ W via MFMA; tile 8 = [a_src | a_dst] ----
// 256 thr = 4 waves; wave = 16 rows; 9 N-tiles x 4 K-steps of 16x16x32 bf16.
__global__ __launch_bounds__(256) void k_gemm_mfma(
    const unsigned short* __restrict__ xb, const unsigned short* __restrict__ wt,
    unsigned short* __restrict__ hb, float* __restrict__ a_src, float* __restrict__ a_dst) {
  const int t = threadIdx.x;
  const int wv = t >> 6, l = t & 63;
  const int lm = l & 15, lk = l >> 4;          // lane -> (free idx, k-block)
  const int r0 = blockIdx.x * 64 + wv * 16;
  const int arow = min(r0 + lm, N_NODES - 1);
  const bf16x8* __restrict__ xv = (const bf16x8*)xb;   // units of 8 elems
  const bf16x8* __restrict__ wv8 = (const bf16x8*)wt;

  f32x4 acc[9];
#pragma unroll
  for (int i = 0; i < 9; ++i) acc[i] = (f32x4){0.f, 0.f, 0.f, 0.f};

#pragma unroll
  for (int kt = 0; kt < 4; ++kt) {
    const int ko8 = kt * 4 + lk;               // (kt*32 + lk*8)/8
    const bf16x8 af = xv[(size_t)arow * 16 + ko8];
#pragma unroll
    for (int nt = 0; nt < 9; ++nt) {
      const bf16x8 bfr = wv8[(nt * 16 + lm) * 16 + ko8];
      acc[nt] = __builtin_amdgcn_mfma_f32_16x16x32_bf16(af, bfr, acc[nt], 0, 0, 0);
    }
  }

  // D layout: row = lk*4 + i, col = lm  (m89-verified)
  const int nd0 = r0 + lk * 4;
#pragma unroll
  for (int i = 0; i < 4; ++i) {
    const int node = nd0 + i;
    if (node < N_NODES) {
#pragma unroll
      for (int nt = 0; nt < 8; ++nt)
        hb[(size_t)node * 128 + nt * 16 + lm] = f2b(acc[nt][i]);
      const float av = acc[8][i];
      if (lm < 8) a_src[node * 8 + lm] = av;
      else a_dst[node * 8 + lm - 8] = av;
    }
  }
}

// ---- 2) histogram of dst degrees (incl. self loops) ----
__global__ void k_hist(const int* __restrict__ ei, int* __restrict__ counts) {
  const int e = blockIdx.x * blockDim.x + threadIdx.x;
  if (e >= E_TOTAL) return;
  const int dst = (e < N_EDGES) ? ei[N_EDGES + e] : (e - N_EDGES);
  atomicAdd(&counts[dst], 1);
}

// ---- 3) exclusive scan of counts -> offs ----
__global__ __launch_bounds__(256) void k_scan1(const int* __restrict__ counts,
                                               int* __restrict__ offs,
                                               int* __restrict__ bsums) {
  __shared__ int s[256];
  const int t = threadIdx.x;
  const int i = blockIdx.x * 256 + t;
  const int c = (i < N_NODES) ? counts[i] : 0;
  s[t] = c;
  __syncthreads();
  for (int off = 1; off < 256; off <<= 1) {
    int v = 0;
    if (t >= off) v = s[t - off];
    __syncthreads();
    if (t >= off) s[t] += v;
    __syncthreads();
  }
  if (i < N_NODES) offs[i] = s[t] - c;
  if (t == 255) bsums[blockIdx.x] = s[255];
}

__global__ __launch_bounds__(256) void k_scan2(int* __restrict__ bsums) {
  __shared__ int s[256];
  const int t = threadIdx.x;
  const int c = (t < SCAN_BLKS) ? bsums[t] : 0;
  s[t] = c;
  __syncthreads();
  for (int off = 1; off < 256; off <<= 1) {
    int v = 0;
    if (t >= off) v = s[t - off];
    __syncthreads();
    if (t >= off) s[t] += v;
    __syncthreads();
  }
  if (t < SCAN_BLKS) bsums[t] = s[t] - c;
}

__global__ __launch_bounds__(256) void k_scan3(int* __restrict__ offs,
                                               const int* __restrict__ bsums) {
  const int i = blockIdx.x * 256 + threadIdx.x;
  if (i < N_NODES) offs[i] += bsums[blockIdx.x];
}

// ---- 4) fill CSR (sorted-by-dst source list) ----
__global__ void k_edge_fill(const int* __restrict__ ei,
                            const int* __restrict__ offs, int* __restrict__ cursor,
                            int* __restrict__ srcs_s) {
  const int e = blockIdx.x * blockDim.x + threadIdx.x;
  if (e >= E_TOTAL) return;
  int src, dst;
  if (e < N_EDGES) {
    src = ei[e];
    dst = ei[N_EDGES + e];
  } else {
    src = dst = e - N_EDGES;
  }
  const int pos = offs[dst] + atomicAdd(&cursor[dst], 1);
  srcs_s[pos] = src;
}

// ---- 5) gather aggregate, one node per wave, half-wave per edge ----
__global__ __launch_bounds__(256) void k_agg(
    const unsigned short* __restrict__ hb, const int* __restrict__ srcs_s,
    const float* __restrict__ a_src, const float* __restrict__ a_dst,
    const int* __restrict__ offs, const int* __restrict__ counts,
    const float* __restrict__ bias, float* __restrict__ out) {
  const int t = threadIdx.x;
  const int wv = t >> 6;        // wave 0..3
  const int l = t & 63;
  const int half = l >> 5;      // edge slot within wave
  const int k = l & 31;         // position in half-wave
  const int hh = k >> 2;        // head (4 lanes x 4 ch = 16 ch/head)
  const uint2* __restrict__ h4 = (const uint2*)hb;

  const int node = blockIdx.x * 4 + wv;
  const int beg = offs[node];
  const int end = beg + counts[node];
  const float adv = a_dst[node * HEADS + hh];

  float a0 = 0.f, a1 = 0.f, a2 = 0.f, a3 = 0.f, den = 0.f;
  int j = beg + half;
  for (; j + 2 < end; j += 4) {   // this half: edges j, j+2
    const int s0 = srcs_s[j];
    const int s1 = srcs_s[j + 2];
    float v0 = a_src[s0 * HEADS + hh] + adv;
    float v1 = a_src[s1 * HEADS + hh] + adv;
    v0 = (v0 > 0.f) ? v0 : NEG_SLOPE * v0;
    v1 = (v1 > 0.f) ? v1 : NEG_SLOPE * v1;
    const uint2 w0 = h4[(size_t)s0 * 32 + k];
    const uint2 w1 = h4[(size_t)s1 * 32 + k];
    const float e0 = __expf(v0);
    const float e1 = __expf(v1);
    den += e0 + e1;
    a0 = fmaf(e0, blo(w0.x), a0);
    a1 = fmaf(e0, bhi(w0.x), a1);
    a2 = fmaf(e0, blo(w0.y), a2);
    a3 = fmaf(e0, bhi(w0.y), a3);
    a0 = fmaf(e1, blo(w1.x), a0);
    a1 = fmaf(e1, bhi(w1.x), a1);
    a2 = fmaf(e1, blo(w1.y), a2);
    a3 = fmaf(e1, bhi(w1.y), a3);
  }
  if (j < end) {                  // tail edge for this half
    const int s0 = srcs_s[j];
    float v0 = a_src[s0 * HEADS + hh] + adv;
    v0 = (v0 > 0.f) ? v0 : NEG_SLOPE * v0;
    const uint2 w0 = h4[(size_t)s0 * 32 + k];
    const float e0 = __expf(v0);
    den += e0;
    a0 = fmaf(e0, blo(w0.x), a0);
    a1 = fmaf(e0, bhi(w0.x), a1);
    a2 = fmaf(e0, blo(w0.y), a2);
    a3 = fmaf(e0, bhi(w0.y), a3);
  }

  // merge the two half-waves (lane k <-> lane k+32 hold the same channels)
  den += __shfl_xor(den, 32);
  a0 += __shfl_xor(a0, 32);
  a1 += __shfl_xor(a1, 32);
  a2 += __shfl_xor(a2, 32);
  a3 += __shfl_xor(a3, 32);

  if (half == 0) {
    const float inv = 1.f / (den + 1e-16f);
    const float4 bv = ((const float4*)bias)[k];
    float4 o;
    o.x = fmaf(a0, inv, bv.x);
    o.y = fmaf(a1, inv, bv.y);
    o.z = fmaf(a2, inv, bv.z);
    o.w = fmaf(a3, inv, bv.w);
    ((float4*)out)[(size_t)node * 32 + k] = o;
  }
}

// ---- 5b) BN stats: grid-stride column sums over out ----
__global__ __launch_bounds__(256) void k_bnstat(const float* __restrict__ out,
                                                float* __restrict__ bnsum,
                                                float* __restrict__ bnsq) {
  const int c = threadIdx.x & 127;
  const int rr = threadIdx.x >> 7;
  float s = 0.f, q = 0.f;
  for (int r = blockIdx.x * 2 + rr; r < N_NODES; r += gridDim.x * 2) {
    const float v = out[(size_t)r * C + c];
    s += v;
    q = fmaf(v, v, q);
  }
  __shared__ float sh[2][128], qh[2][128];
  sh[rr][c] = s;
  qh[rr][c] = q;
  __syncthreads();
  if (threadIdx.x < 128) {
    atomicAdd(&bnsum[c], sh[0][c] + sh[1][c]);
    atomicAdd(&bnsq[c], qh[0][c] + qh[1][c]);
  }
}

// ---- 6) finalize BN scale/shift ----
__global__ __launch_bounds__(128) void k_bnfin(const float* __restrict__ bnsum,
                                               const float* __restrict__ bnsq,
                                               const float* __restrict__ gamma,
                                               const float* __restrict__ beta,
                                               float* __restrict__ scale,
                                               float* __restrict__ shift) {
  const int t = threadIdx.x;
  const float invN = 1.0f / (float)N_NODES;
  const float mean = bnsum[t] * invN;
  const float var = bnsq[t] * invN - mean * mean;
  const float sc = gamma[t] * rsqrtf(var + BN_EPS);
  scale[t] = sc;
  shift[t] = beta[t] - mean * sc;
}

// ---- 7) normalize + ReLU ----
__global__ __launch_bounds__(256) void k_norm(float* __restrict__ out,
                                              const float* __restrict__ scale,
                                              const float* __restrict__ shift) {
  const int i = blockIdx.x * blockDim.x + threadIdx.x;
  if (i >= N_NODES * C / 4) return;
  float4 v = ((float4*)out)[i];
  const int c4 = i & 31;
  const float4 sc = ((const float4*)scale)[c4];
  const float4 sh = ((const float4*)shift)[c4];
  v.x = fmaxf(0.f, fmaf(v.x, sc.x, sh.x));
  v.y = fmaxf(0.f, fmaf(v.y, sc.y, sh.y));
  v.z = fmaxf(0.f, fmaf(v.z, sc.z, sh.z));
  v.w = fmaxf(0.f, fmaf(v.w, sc.w, sh.w));
  ((float4*)out)[i] = v;
}

extern "C" void kernel_launch(void* const* d_in, const int* in_sizes, int n_in,
                              void* d_out, int out_size, void* d_ws, size_t ws_size,
                              hipStream_t stream) {
  const float* x = (const float*)d_in[0];
  const int* ei = (const int*)d_in[1];
  const float* W = (const float*)d_in[2];
  const float* att_src = (const float*)d_in[3];
  const float* att_dst = (const float*)d_in[4];
  const float* bias = (const float*)d_in[5];
  const float* gamma = (const float*)d_in[6];
  const float* beta = (const float*)d_in[7];
  float* out = (float*)d_out;

  char* base = (char*)d_ws;
  size_t off = 0;
  auto alloc = [&](size_t bytes) {
    void* p = base + off;
    off = (off + bytes + 255) & ~(size_t)255;
    return p;
  };

  unsigned short* xb = (unsigned short*)alloc((size_t)N_NODES * C * 2);
  unsigned short* wt = (unsigned short*)alloc((size_t)144 * 128 * 2);
  unsigned short* hb = (unsigned short*)alloc((size_t)N_NODES * C * 2);
  float* a_src = (float*)alloc((size_t)N_NODES * HEADS * 4);
  float* a_dst = (float*)alloc((size_t)N_NODES * HEADS * 4);
  int* srcs_s = (int*)alloc((size_t)E_TOTAL * 4);
  int* offs = (int*)alloc((size_t)N_NODES * 4);
  int* bsums = (int*)alloc(256 * 4);
  float* scale = (float*)alloc(C * 4);
  float* shift = (float*)alloc(C * 4);
  // ---- zeroed region (single memset) ----
  const size_t zoff = off;
  int* counts = (int*)alloc((size_t)N_NODES * 4);
  int* cursor = (int*)alloc((size_t)N_NODES * 4);
  float* bnsum = (float*)alloc(C * 4);
  float* bnsq = (float*)alloc(C * 4);
  const size_t zbytes = off - zoff;
  hipMemsetAsync(base + zoff, 0, zbytes, stream);

  k_prep<<<XB_BLKS + WT_BLKS, 256, 0, stream>>>(x, W, att_src, att_dst, xb, wt);
  k_gemm_mfma<<<(N_NODES + 63) / 64, 256, 0, stream>>>(xb, wt, hb, a_src, a_dst);
  k_hist<<<(E_TOTAL + 255) / 256, 256, 0, stream>>>(ei, counts);
  k_scan1<<<SCAN_BLKS, 256, 0, stream>>>(counts, offs, bsums);
  k_scan2<<<1, 256, 0, stream>>>(bsums);
  k_scan3<<<SCAN_BLKS, 256, 0, stream>>>(offs, bsums);
  k_edge_fill<<<(E_TOTAL + 255) / 256, 256, 0, stream>>>(ei, offs, cursor, srcs_s);
  k_agg<<<N_NODES / 4, 256, 0, stream>>>(hb, srcs_s, a_src, a_dst, offs, counts, bias, out);
  k_bnstat<<<256, 256, 0, stream>>>(out, bnsum, bnsq);
  k_bnfin<<<1, 128, 0, stream>>>(bnsum, bnsq, gamma, beta, scale, shift);
  k_norm<<<(N_NODES * C / 4 + 255) / 256, 256, 0, stream>>>(out, scale, shift);
}